// Round 3
// baseline (252.965 us; speedup 1.0000x reference)
//
#include <hip/hip_runtime.h>
#include <stdint.h>

// ---------------------------------------------------------------------------
// AdjCompute R15: R14 mega-kernel at 1024 threads/block (16 waves/CU,
// 4 waves/SIMD) to double latency hiding. Same 256-block grid, same
// software grid barrier, same phase algebra; work re-split across 16 waves:
//   phase 1: wave w -> column j = w           (was 8 waves x 2 cols)
//   phase 2/3: wave w -> chunk w&7, tiles i ≡ (w>>3) mod 2
//   phase 4: quarter tid>>8 -> tiles i ≡ q mod 4
//   phase 5: 4 tiles per round, 2 syncs, single-buffer transpose
//
// LDS: hbuf 155648 + red[16][32] 2048 + Tm[4][272] 4352 + tdesc 76
//    = 162124 B <= 160 KiB, 1 block/CU.
//
// ws layout (floats), zeroed by k_prep [0..512):
//   [0..128)    stats1  4 x (sum16|ssq16)   stride 32
//   [128..256)  raw2    4 x (S16|Q16)       stride 32
//   [256..320)  stats3  4 x (sum8|ssq8)     stride 16
//   [320..384)  stats4  4 x (sum8|ssq8)     stride 16
//   [384..448)  4 grid-barrier counters, 16-float spacing
//
// Slot layout (8192 B per tile):
//   phase1 h1 / phase2 act1 : pos p, ch c at byte p*32 + c*2
//   phase3 h3 / phase4 act3 : pos p, ch c at byte (p>>5)*1024+(p&31)*16+c*2
// ---------------------------------------------------------------------------

#define NPTS 1536
#define NTILES 4656
#define NBLK 256
#define NTMAX 19
static constexpr float FNN   = 2359296.0f;
static constexpr float EPS   = 1e-5f;
static constexpr float SLOPE = 0.01f;
static constexpr float INV_M = 1.0f / 2359296.0f;

typedef __attribute__((ext_vector_type(8)))  short bf16x8;
typedef __attribute__((ext_vector_type(4)))  float f32x4;
typedef __attribute__((ext_vector_type(16))) float f32x16;
union frag8 { int4 i; bf16x8 v; };

__device__ __forceinline__ float bflo(unsigned u) {
    return __builtin_bit_cast(float, u << 16);
}
__device__ __forceinline__ float bfhi(unsigned u) {
    return __builtin_bit_cast(float, u & 0xffff0000u);
}
__device__ __forceinline__ unsigned short f2bf(float f) {   // RNE
    unsigned u = __builtin_bit_cast(unsigned, f);
    u += 0x7fffu + ((u >> 16) & 1u);
    return (unsigned short)(u >> 16);
}
__device__ __forceinline__ unsigned pack2(float lo, float hi) {  // RNE pair
    return (unsigned)f2bf(lo) | ((unsigned)f2bf(hi) << 16);
}
__device__ __forceinline__ unsigned packtr(float lo, float hi) { // trunc
    unsigned a = __builtin_bit_cast(unsigned, lo);
    unsigned b = __builtin_bit_cast(unsigned, hi);
#if __has_builtin(__builtin_amdgcn_perm)
    return __builtin_amdgcn_perm(b, a, 0x07060302u);
#else
    return (a >> 16) | (b & 0xffff0000u);
#endif
}
__device__ __forceinline__ float lrelu(float t) {
    return fmaxf(t, t * SLOPE);
}
__device__ __forceinline__ float4 ld4(const float* p) {
    return *(const float4*)p;
}
__device__ __forceinline__ unsigned shflx32(unsigned v) {
    return (unsigned)__shfl_xor((int)v, 32);
}

// software grid barrier: one counter per barrier, zeroed by k_prep each launch
__device__ __forceinline__ void gbar(int* ctr) {
    __syncthreads();
    if (threadIdx.x == 0) {
        __threadfence();
        __hip_atomic_fetch_add(ctr, 1, __ATOMIC_RELEASE,
                               __HIP_MEMORY_SCOPE_AGENT);
        while (__hip_atomic_load(ctr, __ATOMIC_ACQUIRE,
                                 __HIP_MEMORY_SCOPE_AGENT) < NBLK) {
            __builtin_amdgcn_s_sleep(4);
        }
        __threadfence();   // invalidate L1 before post-barrier reads
    }
    __syncthreads();
}

// triangle tile decode: t -> (mt, nc), 0<=mt<=nc<96, row-major in mt.
__device__ __forceinline__ int2 tri_decode(int t) {
    float disc = 37249.0f - 8.0f * (float)t;    // 193^2 - 8t
    int mt = (int)((193.0f - sqrtf(disc)) * 0.5f);
    if (mt < 0) mt = 0;
    if (mt > 95) mt = 95;
    while (96 * (mt + 1) - ((mt + 1) * mt) / 2 <= t) mt++;
    while (96 * mt - (mt * (mt - 1)) / 2 > t) mt--;
    int nc = mt + (t - (96 * mt - (mt * (mt - 1)) / 2));
    return make_int2(mt, nc);
}

// bn over 8 channels from 4-replica 8ch stats (replica stride 16)
__device__ __forceinline__ void bn8_inline(
        const float* __restrict__ stats, const float* __restrict__ g,
        const float* __restrict__ be, float* sc, float* sh) {
#pragma unroll
    for (int c = 0; c < 8; c++) {
        float S = stats[c] + stats[16 + c] + stats[32 + c] + stats[48 + c];
        float Q = stats[8 + c] + stats[24 + c] + stats[40 + c] +
                  stats[56 + c];
        float mu  = S * INV_M;
        float var = fmaf(-mu, mu, Q * INV_M);
        float s   = g[c] * rsqrtf(var + EPS);
        sc[c] = s;
        sh[c] = fmaf(-mu, s, be[c]);
    }
}

// --------------------------------------------------------------------------
__global__ __launch_bounds__(256) void k_prep(float* __restrict__ ws) {
    int t = blockIdx.x * 256 + threadIdx.x;
    if (t < 512) ws[t] = 0.0f;
}

// --------------------------------------------------------------------------
__global__ __launch_bounds__(1024, 4) void k_mega(
        const float* __restrict__ x,
        const float* __restrict__ W1, const float* __restrict__ b1,
        const float* __restrict__ g1, const float* __restrict__ be1,
        const float* __restrict__ W2, const float* __restrict__ b2,
        const float* __restrict__ g2, const float* __restrict__ be2,
        const float* __restrict__ W3, const float* __restrict__ b3,
        const float* __restrict__ g3, const float* __restrict__ be3,
        const float* __restrict__ W4, const float* __restrict__ b4,
        const float* __restrict__ g4, const float* __restrict__ be4,
        const float* __restrict__ W5, const float* __restrict__ b5,
        float* __restrict__ out, float* __restrict__ ws) {

    __shared__ unsigned short hbuf[NTMAX * 4096];  // 19 slots * 8192 B
    __shared__ float red[16][32];
    __shared__ float Tm[4][272];                   // [tile-in-round][nl*17+ml]
    __shared__ int tdesc[NTMAX];

    int tid  = threadIdx.x;
    int bid  = blockIdx.x;
    int w    = tid >> 6;           // wave 0..15
    int lane = tid & 63;
    int NT   = 18 + (bid < 48 ? 1 : 0);

    float* stats1 = ws;
    float* raw2   = ws + 128;
    float* stats3 = ws + 256;
    float* stats4 = ws + 320;
    int* bar0 = (int*)(ws + 384);
    int* bar1 = (int*)(ws + 400);
    int* bar2 = (int*)(ws + 416);
    int* bar3 = (int*)(ws + 432);
    int rep32 = (bid & 3) * 32;
    int rep16 = (bid & 3) * 16;

    if (tid < NT) {
        int2 tc = tri_decode(bid + NBLK * tid);
        tdesc[tid] = (tc.x << 8) | tc.y;
    }
    __syncthreads();

    // ---------------- phase 1: h1 -> LDS + weighted stats1 ----------------
    // wave w computes column j = w of every tile.
    {
        int l15 = lane & 15, quad = lane >> 4, cb = quad * 8;
        const float* wr = W1 + l15 * 64 + cb;
        float4 w0 = ld4(wr);
        float4 w1v = ld4(wr + 4);
        float4 w2v = ld4(wr + 32);
        float4 w3v = ld4(wr + 36);
        frag8 fb1, fb2;
        fb1.i = make_int4(pack2(w0.x, w0.y), pack2(w0.z, w0.w),
                          pack2(w1v.x, w1v.y), pack2(w1v.z, w1v.w));
        fb2.i = make_int4(pack2(w2v.x, w2v.y), pack2(w2v.z, w2v.w),
                          pack2(w3v.x, w3v.y), pack2(w3v.z, w3v.w));
        float4 b1v = ld4(b1 + quad * 4);
        float lsum[4] = {0.f, 0.f, 0.f, 0.f};
        float lssq[4] = {0.f, 0.f, 0.f, 0.f};

#pragma unroll 1
        for (int i = 0; i < NT; i++) {
            int td = tdesc[i];
            int mt = td >> 8, nc = td & 255;
            float wf = (mt == nc) ? 1.0f : 2.0f;
            const float* xr = x + (mt * 16 + l15) * 64 + cb;
            float4 xa0 = ld4(xr);
            float4 xa1 = ld4(xr + 4);
            float4 xa2 = ld4(xr + 32);
            float4 xa3 = ld4(xr + 36);
            const float* xp = x + (size_t)(nc * 16 + w) * 64 + cb;
            float4 u0 = ld4(xp);
            float4 u1 = ld4(xp + 4);
            float4 u2 = ld4(xp + 32);
            float4 u3 = ld4(xp + 36);

            frag8 fa1, fa2;
            fa1.i = make_int4(
                packtr(fabsf(xa0.x - u0.x), fabsf(xa0.y - u0.y)),
                packtr(fabsf(xa0.z - u0.z), fabsf(xa0.w - u0.w)),
                packtr(fabsf(xa1.x - u1.x), fabsf(xa1.y - u1.y)),
                packtr(fabsf(xa1.z - u1.z), fabsf(xa1.w - u1.w)));
            fa2.i = make_int4(
                packtr(fabsf(xa2.x - u2.x), fabsf(xa2.y - u2.y)),
                packtr(fabsf(xa2.z - u2.z), fabsf(xa2.w - u2.w)),
                packtr(fabsf(xa3.x - u3.x), fabsf(xa3.y - u3.y)),
                packtr(fabsf(xa3.z - u3.z), fabsf(xa3.w - u3.w)));
            f32x4 acc = {b1v.x, b1v.y, b1v.z, b1v.w};
            acc = __builtin_amdgcn_mfma_f32_16x16x32_bf16(fb1.v, fa1.v,
                                                          acc, 0, 0, 0);
            acc = __builtin_amdgcn_mfma_f32_16x16x32_bf16(fb2.v, fa2.v,
                                                          acc, 0, 0, 0);
#pragma unroll
            for (int r = 0; r < 4; r++) {
                float wa = wf * acc[r];
                lsum[r] += wa;
                lssq[r] = fmaf(wa, acc[r], lssq[r]);
            }
            *(uint2*)(hbuf + i * 4096 + w * 256 + l15 * 16 + quad * 4) =
                make_uint2(pack2(acc[0], acc[1]), pack2(acc[2], acc[3]));
        }
#pragma unroll
        for (int off = 1; off < 16; off <<= 1) {
#pragma unroll
            for (int r = 0; r < 4; r++) {
                lsum[r] += __shfl_xor(lsum[r], off);
                lssq[r] += __shfl_xor(lssq[r], off);
            }
        }
        if (l15 == 0) {
#pragma unroll
            for (int r = 0; r < 4; r++) {
                red[w][quad * 4 + r]      = lsum[r];
                red[w][16 + quad * 4 + r] = lssq[r];
            }
        }
        __syncthreads();
        if (tid < 32) {
            float v = 0.f;
#pragma unroll
            for (int k = 0; k < 16; k++) v += red[k][tid];
            atomicAdd(stats1 + rep32 + tid, v);
        }
    }
    gbar(bar0);

    // ---------------- phase 2: moments of d2; write act1 back in place ----
    // wave w: chunk c = w&7 (32 positions), tiles i ≡ (w>>3) mod 2.
    {
        int pc = lane & 31, kh = lane >> 5;
        int ck = w & 7, g = w >> 3;
        float sc[8], sh[8];
#pragma unroll
        for (int jc = 0; jc < 8; jc++) {
            int c = kh * 8 + jc;
            float S = stats1[c] + stats1[32 + c] + stats1[64 + c] +
                      stats1[96 + c];
            float Q = stats1[16 + c] + stats1[48 + c] + stats1[80 + c] +
                      stats1[112 + c];
            float mu  = S * INV_M;
            float var = fmaf(-mu, mu, Q * INV_M);
            float s   = g1[c] * rsqrtf(var + EPS);
            sc[jc] = s;
            sh[jc] = fmaf(-mu, s, be1[c]);
        }
        frag8 fw2; fw2.i = make_int4(0, 0, 0, 0);
        if (pc < 16) {
            const float* wp = W2 + pc * 16 + kh * 8;
            float4 wa = ld4(wp), wb = ld4(wp + 4);
            fw2.i = make_int4(pack2(wa.x, wa.y), pack2(wa.z, wa.w),
                              pack2(wb.x, wb.y), pack2(wb.z, wb.w));
        }
        f32x16 z;
#pragma unroll
        for (int r = 0; r < 16; r++) z[r] = 0.0f;
        float sum2[8], ssq2[8];
#pragma unroll
        for (int r = 0; r < 8; r++) { sum2[r] = 0.f; ssq2[r] = 0.f; }

        int base = ck * 512 + pc * 16 + kh * 8;   // ushort offset in slot

        auto body2 = [&](int i, uint4 v) {
            int td = tdesc[i];
            float wf = ((td >> 8) == (td & 255)) ? 1.0f : 2.0f;
            float a0 = bflo(v.x), a1 = bfhi(v.x);
            float a2 = bflo(v.y), a3 = bfhi(v.y);
            float a4 = bflo(v.z), a5 = bfhi(v.z);
            float a6 = bflo(v.w), a7 = bfhi(v.w);
            a0 = lrelu(fmaf(a0, sc[0], sh[0]));
            a1 = lrelu(fmaf(a1, sc[1], sh[1]));
            a2 = lrelu(fmaf(a2, sc[2], sh[2]));
            a3 = lrelu(fmaf(a3, sc[3], sh[3]));
            a4 = lrelu(fmaf(a4, sc[4], sh[4]));
            a5 = lrelu(fmaf(a5, sc[5], sh[5]));
            a6 = lrelu(fmaf(a6, sc[6], sh[6]));
            a7 = lrelu(fmaf(a7, sc[7], sh[7]));
            frag8 fbv;
            fbv.i = make_int4(packtr(a0, a1), packtr(a2, a3),
                              packtr(a4, a5), packtr(a6, a7));
            // write act1 back over h1 (wave-exclusive region per tile)
            *(uint4*)(hbuf + i * 4096 + base) =
                make_uint4(fbv.i.x, fbv.i.y, fbv.i.z, fbv.i.w);
            f32x16 d = __builtin_amdgcn_mfma_f32_32x32x16_bf16(fw2.v, fbv.v,
                                                               z, 0, 0, 0);
#pragma unroll
            for (int r = 0; r < 8; r++) {
                float dv = d[r];
                float wd = wf * dv;
                sum2[r] += wd;
                ssq2[r] = fmaf(wd, dv, ssq2[r]);
            }
        };

        uint4 v = make_uint4(0, 0, 0, 0);
        if (g < NT) v = *(const uint4*)(hbuf + g * 4096 + base);
#pragma unroll 1
        for (int i = g; i < NT; i += 2) {
            uint4 vn = v;
            if (i + 2 < NT)
                vn = *(const uint4*)(hbuf + (i + 2) * 4096 + base);
            body2(i, v);
            v = vn;
        }

#pragma unroll
        for (int off = 1; off < 32; off <<= 1) {
#pragma unroll
            for (int r = 0; r < 8; r++) {
                sum2[r] += __shfl_xor(sum2[r], off);
                ssq2[r] += __shfl_xor(ssq2[r], off);
            }
        }
        if (pc == 0) {
#pragma unroll
            for (int r = 0; r < 8; r++) {
                int o = (r & 3) + 8 * (r >> 2) + 4 * kh;
                red[w][o]      = sum2[r];
                red[w][16 + o] = ssq2[r];
            }
        }
        __syncthreads();
        if (tid < 32) {
            float v2 = 0.f;
#pragma unroll
            for (int k = 0; k < 16; k++) v2 += red[k][tid];
            atomicAdd(raw2 + rep32 + tid, v2);
        }
    }
    gbar(bar1);

    // ---------------- phase 3: act1 -> d2 -> act2 -> h3 (wave-private) ----
    {
        int pc = lane & 31, kh = lane >> 5;
        int ck = w & 7, g = w >> 3;
        float sc2[8], sh2[8];
#pragma unroll
        for (int r = 0; r < 8; r++) {
            int c = (r & 3) + 8 * (r >> 2) + 4 * kh;
            float S = raw2[c] + raw2[32 + c] + raw2[64 + c] + raw2[96 + c];
            float Q = raw2[16 + c] + raw2[48 + c] + raw2[80 + c] +
                      raw2[112 + c];
            float bc = b2[c];
            float sm = S + FNN * bc;
            float sq = Q + 2.0f * bc * S + FNN * bc * bc;
            float mu  = sm * INV_M;
            float var = fmaf(-mu, mu, sq * INV_M);
            float s   = g2[c] * rsqrtf(var + EPS);
            float shv = fmaf(-mu, s, be2[c]);
            sc2[r] = s;
            sh2[r] = fmaf(s, bc, shv);
        }
        frag8 fw2; fw2.i = make_int4(0, 0, 0, 0);
        if (pc < 16) {
            const float* wp = W2 + pc * 16 + kh * 8;
            float4 wa = ld4(wp), wb = ld4(wp + 4);
            fw2.i = make_int4(pack2(wa.x, wa.y), pack2(wa.z, wa.w),
                              pack2(wb.x, wb.y), pack2(wb.z, wb.w));
        }
        frag8 fw3; fw3.i = make_int4(0, 0, 0, 0);
        if (pc < 8) {
            const float* wp = W3 + pc * 16 + kh * 8;
            float4 wa = ld4(wp), wb = ld4(wp + 4);
            fw3.i = make_int4(pack2(wa.x, wa.y), pack2(wa.z, wa.w),
                              pack2(wb.x, wb.y), pack2(wb.z, wb.w));
        }
        float b3r[4];
#pragma unroll
        for (int r = 0; r < 4; r++) b3r[r] = b3[kh * 4 + r];
        f32x16 z;
#pragma unroll
        for (int r = 0; r < 16; r++) z[r] = 0.0f;
        float sum3[4] = {0.f, 0.f, 0.f, 0.f};
        float ssq3[4] = {0.f, 0.f, 0.f, 0.f};

        int rbase = ck * 512 + pc * 16 + kh * 8;   // act1 read (ushorts)
        int wbase = ck * 512 + pc * 8 + kh * 4;    // h3 write (ushorts)

        uint4 v = make_uint4(0, 0, 0, 0);
        if (g < NT) v = *(const uint4*)(hbuf + g * 4096 + rbase);
#pragma unroll 1
        for (int i = g; i < NT; i += 2) {
            uint4 vn = v;
            if (i + 2 < NT)
                vn = *(const uint4*)(hbuf + (i + 2) * 4096 + rbase);
            int td = tdesc[i];
            float wf = ((td >> 8) == (td & 255)) ? 1.0f : 2.0f;
            frag8 fbv;
            fbv.i = make_int4((int)v.x, (int)v.y, (int)v.z, (int)v.w);
            f32x16 d = __builtin_amdgcn_mfma_f32_32x32x16_bf16(fw2.v, fbv.v,
                                                               z, 0, 0, 0);
            float t0 = lrelu(fmaf(d[0], sc2[0], sh2[0]));
            float t1 = lrelu(fmaf(d[1], sc2[1], sh2[1]));
            float t2 = lrelu(fmaf(d[2], sc2[2], sh2[2]));
            float t3 = lrelu(fmaf(d[3], sc2[3], sh2[3]));
            float t4 = lrelu(fmaf(d[4], sc2[4], sh2[4]));
            float t5 = lrelu(fmaf(d[5], sc2[5], sh2[5]));
            float t6 = lrelu(fmaf(d[6], sc2[6], sh2[6]));
            float t7 = lrelu(fmaf(d[7], sc2[7], sh2[7]));
            unsigned e0 = packtr(t0, t1), e1 = packtr(t2, t3);
            unsigned e2 = packtr(t4, t5), e3 = packtr(t6, t7);
            unsigned p0 = kh ? e0 : e2;
            unsigned p1 = kh ? e1 : e3;
            unsigned q0 = shflx32(p0);
            unsigned q1 = shflx32(p1);
            frag8 fb2;
            fb2.i = make_int4(kh ? q0 : e0, kh ? q1 : e1,
                              kh ? e2 : q0, kh ? e3 : q1);
            f32x16 d2 = __builtin_amdgcn_mfma_f32_32x32x16_bf16(fw3.v, fb2.v,
                                                                z, 0, 0, 0);
            float h0  = d2[0] + b3r[0];
            float h1v = d2[1] + b3r[1];
            float h2v = d2[2] + b3r[2];
            float h3v = d2[3] + b3r[3];
            float wh;
            wh = wf * h0;  sum3[0] += wh; ssq3[0] = fmaf(wh, h0,  ssq3[0]);
            wh = wf * h1v; sum3[1] += wh; ssq3[1] = fmaf(wh, h1v, ssq3[1]);
            wh = wf * h2v; sum3[2] += wh; ssq3[2] = fmaf(wh, h2v, ssq3[2]);
            wh = wf * h3v; sum3[3] += wh; ssq3[3] = fmaf(wh, h3v, ssq3[3]);
            *(uint2*)(hbuf + i * 4096 + wbase) =
                make_uint2(pack2(h0, h1v), pack2(h2v, h3v));
            v = vn;
        }
#pragma unroll
        for (int off = 1; off < 32; off <<= 1) {
#pragma unroll
            for (int r = 0; r < 4; r++) {
                sum3[r] += __shfl_xor(sum3[r], off);
                ssq3[r] += __shfl_xor(ssq3[r], off);
            }
        }
        if (pc == 0) {
#pragma unroll
            for (int r = 0; r < 4; r++) {
                red[w][kh * 4 + r]     = sum3[r];
                red[w][8 + kh * 4 + r] = ssq3[r];
            }
        }
        __syncthreads();
        if (tid < 16) {
            float v2 = 0.f;
#pragma unroll
            for (int k = 0; k < 16; k++) v2 += red[k][tid];
            atomicAdd(stats3 + rep16 + tid, v2);
        }
    }
    gbar(bar2);

    // ---------------- phase 4: moments of h4; write act3 back in place ----
    // quarter q = tid>>8 handles tiles i ≡ q (mod 4).
    {
        float sc3[8], sh3[8];
        bn8_inline(stats3, g3, be3, sc3, sh3);
        int q = tid >> 8;
        int p = tid & 255;
        int pbase = (p >> 5) * 512 + (p & 31) * 8;   // ushort offset in slot

        float w4r[8][8], bi[8];
#pragma unroll
        for (int o = 0; o < 8; o++) {
            const float* wr = W4 + o * 8;
            float4 v0 = ld4(wr);
            float4 v1 = ld4(wr + 4);
            w4r[o][0] = v0.x; w4r[o][1] = v0.y;
            w4r[o][2] = v0.z; w4r[o][3] = v0.w;
            w4r[o][4] = v1.x; w4r[o][5] = v1.y;
            w4r[o][6] = v1.z; w4r[o][7] = v1.w;
            bi[o] = b4[o];
        }
        float sum4[8], ssq4[8];
#pragma unroll
        for (int o = 0; o < 8; o++) { sum4[o] = 0.f; ssq4[o] = 0.f; }

        uint4 v = make_uint4(0, 0, 0, 0);
        if (q < NT) v = *(const uint4*)(hbuf + q * 4096 + pbase);
#pragma unroll 1
        for (int i = q; i < NT; i += 4) {
            uint4 vn = v;
            if (i + 4 < NT)
                vn = *(const uint4*)(hbuf + (i + 4) * 4096 + pbase);
            int td = tdesc[i];
            float wf = ((td >> 8) == (td & 255)) ? 1.0f : 2.0f;
            float a0 = bflo(v.x), a1 = bfhi(v.x);
            float a2 = bflo(v.y), a3 = bfhi(v.y);
            float a4 = bflo(v.z), a5 = bfhi(v.z);
            float a6 = bflo(v.w), a7 = bfhi(v.w);
            a0 = lrelu(fmaf(a0, sc3[0], sh3[0]));
            a1 = lrelu(fmaf(a1, sc3[1], sh3[1]));
            a2 = lrelu(fmaf(a2, sc3[2], sh3[2]));
            a3 = lrelu(fmaf(a3, sc3[3], sh3[3]));
            a4 = lrelu(fmaf(a4, sc3[4], sh3[4]));
            a5 = lrelu(fmaf(a5, sc3[5], sh3[5]));
            a6 = lrelu(fmaf(a6, sc3[6], sh3[6]));
            a7 = lrelu(fmaf(a7, sc3[7], sh3[7]));
            uint4 pk = make_uint4(pack2(a0, a1), pack2(a2, a3),
                                  pack2(a4, a5), pack2(a6, a7));
            *(uint4*)(hbuf + i * 4096 + pbase) = pk;   // act3 write-back
            // use the bf16-rounded act3 (self-consistent with phase 5)
            float r[8];
            r[0] = bflo(pk.x); r[1] = bfhi(pk.x);
            r[2] = bflo(pk.y); r[3] = bfhi(pk.y);
            r[4] = bflo(pk.z); r[5] = bfhi(pk.z);
            r[6] = bflo(pk.w); r[7] = bfhi(pk.w);
            float d[8];
#pragma unroll
            for (int o = 0; o < 8; o++) d[o] = bi[o];
#pragma unroll
            for (int c = 0; c < 8; c++) {
#pragma unroll
                for (int o = 0; o < 8; o++)
                    d[o] = fmaf(r[c], w4r[o][c], d[o]);
            }
#pragma unroll
            for (int o = 0; o < 8; o++) {
                float wd = wf * d[o];
                sum4[o] += wd;
                ssq4[o] = fmaf(wd, d[o], ssq4[o]);
            }
            v = vn;
        }
        // each wave lies wholly within one quarter -> full 64-lane reduce
#pragma unroll
        for (int off = 1; off < 64; off <<= 1) {
#pragma unroll
            for (int o = 0; o < 8; o++) {
                sum4[o] += __shfl_xor(sum4[o], off);
                ssq4[o] += __shfl_xor(ssq4[o], off);
            }
        }
        if (lane == 0) {
#pragma unroll
            for (int o = 0; o < 8; o++) {
                red[w][o]     = sum4[o];
                red[w][8 + o] = ssq4[o];
            }
        }
        __syncthreads();
        if (tid < 16) {
            float v2 = 0.f;
#pragma unroll
            for (int k = 0; k < 16; k++) v2 += red[k][tid];
            atomicAdd(stats4 + rep16 + tid, v2);
        }
    }
    gbar(bar3);

    // ---------------- phase 5: out tile + LDS-transposed mirror -----------
    // 4 tiles per round (q = tid>>8), single-buffer Tm, 2 syncs/round.
    {
        float w4f[8][8], b4f[8], w5r[8];
#pragma unroll
        for (int o = 0; o < 8; o++) {
            float S = stats4[o] + stats4[16 + o] + stats4[32 + o] +
                      stats4[48 + o];
            float Q = stats4[8 + o] + stats4[24 + o] + stats4[40 + o] +
                      stats4[56 + o];
            float mu  = S * INV_M;
            float var = fmaf(-mu, mu, Q * INV_M);
            float s   = g4[o] * rsqrtf(var + EPS);
            float shv = fmaf(-mu, s, be4[o]);
            b4f[o] = fmaf(s, b4[o], shv);
            const float* wr = W4 + o * 8;
            float4 v0 = ld4(wr);
            float4 v1 = ld4(wr + 4);
            w4f[o][0] = s * v0.x; w4f[o][1] = s * v0.y;
            w4f[o][2] = s * v0.z; w4f[o][3] = s * v0.w;
            w4f[o][4] = s * v1.x; w4f[o][5] = s * v1.y;
            w4f[o][6] = s * v1.z; w4f[o][7] = s * v1.w;
            w5r[o] = W5[o];
        }
        float b5v = b5[0];
        int q  = tid >> 8;
        int lt = tid & 255;
        int nl = lt >> 4, ml = lt & 15;
        int pbase = (lt >> 5) * 512 + (lt & 31) * 8;
        int nround = (NT + 3) >> 2;

#pragma unroll 1
        for (int jp = 0; jp < nround; jp++) {
            int i = 4 * jp + q;
            bool act = (i < NT);
            int mt = 0, nc = 0;
            if (act) {
                int td = tdesc[i];
                mt = td >> 8; nc = td & 255;
                uint4 v = *(const uint4*)(hbuf + i * 4096 + pbase);
                float a[8];   // act3, already BN3+lrelu'd
                a[0] = bflo(v.x); a[1] = bfhi(v.x);
                a[2] = bflo(v.y); a[3] = bfhi(v.y);
                a[4] = bflo(v.z); a[5] = bfhi(v.z);
                a[6] = bflo(v.w); a[7] = bfhi(v.w);
                float accv = b5v;
#pragma unroll
                for (int o = 0; o < 8; o++) {
                    float hh = b4f[o];
#pragma unroll
                    for (int c = 0; c < 8; c++)
                        hh = fmaf(a[c], w4f[o][c], hh);
                    accv = fmaf(lrelu(hh), w5r[o], accv);
                }
                out[(size_t)(nc * 16 + nl) * NPTS + mt * 16 + ml] = accv;
                Tm[q][nl * 17 + ml] = accv;
            }
            __syncthreads();
            if (act) {
                float mv = Tm[q][ml * 17 + nl];
                out[(size_t)(mt * 16 + nl) * NPTS + nc * 16 + ml] = mv;
            }
            __syncthreads();
        }
    }
}

// --------------------------------------------------------------------------
extern "C" void kernel_launch(void* const* d_in, const int* in_sizes, int n_in,
                              void* d_out, int out_size, void* d_ws,
                              size_t ws_size, hipStream_t stream) {
    const float* x   = (const float*)d_in[0];
    const float* W1  = (const float*)d_in[1];
    const float* b1  = (const float*)d_in[2];
    const float* g1  = (const float*)d_in[3];
    const float* be1 = (const float*)d_in[4];
    const float* W2  = (const float*)d_in[5];
    const float* b2  = (const float*)d_in[6];
    const float* g2  = (const float*)d_in[7];
    const float* be2 = (const float*)d_in[8];
    const float* W3  = (const float*)d_in[9];
    const float* b3  = (const float*)d_in[10];
    const float* g3  = (const float*)d_in[11];
    const float* be3 = (const float*)d_in[12];
    const float* W4  = (const float*)d_in[13];
    const float* b4  = (const float*)d_in[14];
    const float* g4  = (const float*)d_in[15];
    const float* be4 = (const float*)d_in[16];
    const float* W5  = (const float*)d_in[17];
    const float* b5  = (const float*)d_in[18];

    float* ws   = (float*)d_ws;
    float* outp = (float*)d_out;

    k_prep<<<2, 256, 0, stream>>>(ws);
    k_mega<<<NBLK, 1024, 0, stream>>>(
        x, W1, b1, g1, be1, W2, b2, g2, be2, W3, b3, g3, be3,
        W4, b4, g4, be4, W5, b5, outp, ws);
}

// Round 5
// 232.014 us; speedup vs baseline: 1.0903x; 1.0903x over previous
//
#include <hip/hip_runtime.h>
#include <stdint.h>

// ---------------------------------------------------------------------------
// AdjCompute R17: R16 resubmit with hardened flag-array grid barrier.
// R16 bench failed with no counters (infra flake or barrier hang); the
// barrier fence discipline is the only structurally-new sync object, so it
// is rebuilt conservatively:
//   - 256 threads poll exactly one flag each (uniform exec, 4 waves)
//   - relaxed polls -> __syncthreads -> thread-0 __threadfence (L1
//     invalidate strictly after ALL polls) -> __syncthreads
// Everything else identical to R16:
//   - 16-replica stats (4x less atomic line contention than R14)
//   - phase-1 cross-tile register prefetch (TSet ping-pong)
//   - act1/act3 in-place write-back, wave-private phase 3, phase-5
//     double-buffered transpose mirror
//
// 256 blocks x 512 threads, 1 block/CU, co-resident (proven R14/R15).
// LDS: hbuf 155648 + red 1KB + Tm 4.25KB + tdesc = ~157.3 KB.
//
// ws layout (floats), zeroed by k_prep [0..5632):
//   [0..512)     stats1  16 x (sum16|ssq16)  stride 32
//   [512..1024)  raw2    16 x (S16|Q16)      stride 32
//   [1024..1280) stats3  16 x (sum8|ssq8)    stride 16
//   [1280..1536) stats4  16 x (sum8|ssq8)    stride 16
//   [1536..5632) flags: 256 blocks x 16 ints (64B spacing), epoch counters
//
// Slot layout (8192 B per tile):
//   phase1 h1 / phase2 act1 : pos p, ch c at byte p*32 + c*2
//   phase3 h3 / phase4 act3 : pos p, ch c at byte (p>>5)*1024+(p&31)*16+c*2
// ---------------------------------------------------------------------------

#define NPTS 1536
#define NTILES 4656
#define NBLK 256
#define NTMAX 19
static constexpr float FNN   = 2359296.0f;
static constexpr float EPS   = 1e-5f;
static constexpr float SLOPE = 0.01f;
static constexpr float INV_M = 1.0f / 2359296.0f;

typedef __attribute__((ext_vector_type(8)))  short bf16x8;
typedef __attribute__((ext_vector_type(4)))  float f32x4;
typedef __attribute__((ext_vector_type(16))) float f32x16;
union frag8 { int4 i; bf16x8 v; };

__device__ __forceinline__ float bflo(unsigned u) {
    return __builtin_bit_cast(float, u << 16);
}
__device__ __forceinline__ float bfhi(unsigned u) {
    return __builtin_bit_cast(float, u & 0xffff0000u);
}
__device__ __forceinline__ unsigned short f2bf(float f) {   // RNE
    unsigned u = __builtin_bit_cast(unsigned, f);
    u += 0x7fffu + ((u >> 16) & 1u);
    return (unsigned short)(u >> 16);
}
__device__ __forceinline__ unsigned pack2(float lo, float hi) {  // RNE pair
    return (unsigned)f2bf(lo) | ((unsigned)f2bf(hi) << 16);
}
__device__ __forceinline__ unsigned packtr(float lo, float hi) { // trunc
    unsigned a = __builtin_bit_cast(unsigned, lo);
    unsigned b = __builtin_bit_cast(unsigned, hi);
#if __has_builtin(__builtin_amdgcn_perm)
    return __builtin_amdgcn_perm(b, a, 0x07060302u);
#else
    return (a >> 16) | (b & 0xffff0000u);
#endif
}
__device__ __forceinline__ float lrelu(float t) {
    return fmaxf(t, t * SLOPE);
}
__device__ __forceinline__ float4 ld4(const float* p) {
    return *(const float4*)p;
}
__device__ __forceinline__ unsigned shflx32(unsigned v) {
    return (unsigned)__shfl_xor((int)v, 32);
}

// flag-array grid barrier, hardened:
//   arrive:  thread 0: fence (drain my stats atomics) + release-store epoch
//   wait:    threads 0..255 each poll ONE flag (relaxed)
//   publish: syncthreads -> thread-0 threadfence (L1 invalidate AFTER all
//            polls) -> syncthreads
__device__ __forceinline__ void gbar(int* flags, int epoch) {
    __syncthreads();
    if (threadIdx.x == 0) {
        __threadfence();
        __hip_atomic_store(flags + (int)blockIdx.x * 16, epoch,
                           __ATOMIC_RELEASE, __HIP_MEMORY_SCOPE_AGENT);
    }
    if (threadIdx.x < 256) {
        const int* f = flags + (int)threadIdx.x * 16;
        while (__hip_atomic_load(f, __ATOMIC_RELAXED,
                                 __HIP_MEMORY_SCOPE_AGENT) < epoch) {
            __builtin_amdgcn_s_sleep(2);
        }
    }
    __syncthreads();
    if (threadIdx.x == 0) __threadfence();   // invalidate caches post-arrival
    __syncthreads();
}

// triangle tile decode: t -> (mt, nc), 0<=mt<=nc<96, row-major in mt.
__device__ __forceinline__ int2 tri_decode(int t) {
    float disc = 37249.0f - 8.0f * (float)t;    // 193^2 - 8t
    int mt = (int)((193.0f - sqrtf(disc)) * 0.5f);
    if (mt < 0) mt = 0;
    if (mt > 95) mt = 95;
    while (96 * (mt + 1) - ((mt + 1) * mt) / 2 <= t) mt++;
    while (96 * mt - (mt * (mt - 1)) / 2 > t) mt--;
    int nc = mt + (t - (96 * mt - (mt * (mt - 1)) / 2));
    return make_int2(mt, nc);
}

// bn over 8 channels from 16-replica 8ch stats (replica stride 16)
__device__ __forceinline__ void bn8_inline(
        const float* __restrict__ stats, const float* __restrict__ g,
        const float* __restrict__ be, float* sc, float* sh) {
#pragma unroll
    for (int c = 0; c < 8; c++) {
        float S = 0.f, Q = 0.f;
#pragma unroll
        for (int rp = 0; rp < 16; rp++) {
            S += stats[rp * 16 + c];
            Q += stats[rp * 16 + 8 + c];
        }
        float mu  = S * INV_M;
        float var = fmaf(-mu, mu, Q * INV_M);
        float s   = g[c] * rsqrtf(var + EPS);
        sc[c] = s;
        sh[c] = fmaf(-mu, s, be[c]);
    }
}

// --------------------------------------------------------------------------
__global__ __launch_bounds__(256) void k_prep(float* __restrict__ ws) {
    int t = blockIdx.x * 256 + threadIdx.x;
    if (t < 5632) ws[t] = 0.0f;
}

// --------------------------------------------------------------------------
struct TSet {
    float4 a0, a1, a2, a3;   // xa rows (mt*16 + l15)
    float4 p0, p1, p2, p3;   // u col 2w
    float4 q0, q1, q2, q3;   // u col 2w+1
};

__global__ __launch_bounds__(512, 2) void k_mega(
        const float* __restrict__ x,
        const float* __restrict__ W1, const float* __restrict__ b1,
        const float* __restrict__ g1, const float* __restrict__ be1,
        const float* __restrict__ W2, const float* __restrict__ b2,
        const float* __restrict__ g2, const float* __restrict__ be2,
        const float* __restrict__ W3, const float* __restrict__ b3,
        const float* __restrict__ g3, const float* __restrict__ be3,
        const float* __restrict__ W4, const float* __restrict__ b4,
        const float* __restrict__ g4, const float* __restrict__ be4,
        const float* __restrict__ W5, const float* __restrict__ b5,
        float* __restrict__ out, float* __restrict__ ws) {

    __shared__ unsigned short hbuf[NTMAX * 4096];  // 19 slots * 8192 B
    __shared__ float red[8][32];
    __shared__ float Tm[2][2][272];                // [buf][half][nl*17+ml]
    __shared__ int tdesc[NTMAX];

    int tid  = threadIdx.x;
    int bid  = blockIdx.x;
    int w    = tid >> 6;
    int lane = tid & 63;
    int NT   = 18 + (bid < 48 ? 1 : 0);

    float* stats1 = ws;
    float* raw2   = ws + 512;
    float* stats3 = ws + 1024;
    float* stats4 = ws + 1280;
    int* flags    = (int*)(ws + 1536);
    int rep32 = (bid & 15) * 32;
    int rep16 = (bid & 15) * 16;

    if (tid < NT) {
        int2 tc = tri_decode(bid + NBLK * tid);
        tdesc[tid] = (tc.x << 8) | tc.y;
    }
    __syncthreads();

    // ---------------- phase 1: h1 -> LDS + weighted stats1 ----------------
    {
        int l15 = lane & 15, quad = lane >> 4, cb = quad * 8;
        const float* wr = W1 + l15 * 64 + cb;
        float4 w0 = ld4(wr);
        float4 w1v = ld4(wr + 4);
        float4 w2v = ld4(wr + 32);
        float4 w3v = ld4(wr + 36);
        frag8 fb1, fb2;
        fb1.i = make_int4(pack2(w0.x, w0.y), pack2(w0.z, w0.w),
                          pack2(w1v.x, w1v.y), pack2(w1v.z, w1v.w));
        fb2.i = make_int4(pack2(w2v.x, w2v.y), pack2(w2v.z, w2v.w),
                          pack2(w3v.x, w3v.y), pack2(w3v.z, w3v.w));
        float4 b1v = ld4(b1 + quad * 4);
        float lsum[4] = {0.f, 0.f, 0.f, 0.f};
        float lssq[4] = {0.f, 0.f, 0.f, 0.f};

        auto loadT = [&](int i, TSet& s) {
            int td = tdesc[i];
            int mt = td >> 8, nc = td & 255;
            const float* xr = x + (mt * 16 + l15) * 64 + cb;
            s.a0 = ld4(xr); s.a1 = ld4(xr + 4);
            s.a2 = ld4(xr + 32); s.a3 = ld4(xr + 36);
            const float* pA = x + (size_t)(nc * 16 + 2 * w) * 64 + cb;
            s.p0 = ld4(pA); s.p1 = ld4(pA + 4);
            s.p2 = ld4(pA + 32); s.p3 = ld4(pA + 36);
            const float* pB = x + (size_t)(nc * 16 + 2 * w + 1) * 64 + cb;
            s.q0 = ld4(pB); s.q1 = ld4(pB + 4);
            s.q2 = ld4(pB + 32); s.q3 = ld4(pB + 36);
        };
        auto colT = [&](int i, float wf, int j, float4 u0, float4 u1,
                        float4 u2, float4 u3, const TSet& s) {
            frag8 fa1, fa2;
            fa1.i = make_int4(
                packtr(fabsf(s.a0.x - u0.x), fabsf(s.a0.y - u0.y)),
                packtr(fabsf(s.a0.z - u0.z), fabsf(s.a0.w - u0.w)),
                packtr(fabsf(s.a1.x - u1.x), fabsf(s.a1.y - u1.y)),
                packtr(fabsf(s.a1.z - u1.z), fabsf(s.a1.w - u1.w)));
            fa2.i = make_int4(
                packtr(fabsf(s.a2.x - u2.x), fabsf(s.a2.y - u2.y)),
                packtr(fabsf(s.a2.z - u2.z), fabsf(s.a2.w - u2.w)),
                packtr(fabsf(s.a3.x - u3.x), fabsf(s.a3.y - u3.y)),
                packtr(fabsf(s.a3.z - u3.z), fabsf(s.a3.w - u3.w)));
            f32x4 acc = {b1v.x, b1v.y, b1v.z, b1v.w};
            acc = __builtin_amdgcn_mfma_f32_16x16x32_bf16(fb1.v, fa1.v,
                                                          acc, 0, 0, 0);
            acc = __builtin_amdgcn_mfma_f32_16x16x32_bf16(fb2.v, fa2.v,
                                                          acc, 0, 0, 0);
#pragma unroll
            for (int r = 0; r < 4; r++) {
                float wa = wf * acc[r];
                lsum[r] += wa;
                lssq[r] = fmaf(wa, acc[r], lssq[r]);
            }
            *(uint2*)(hbuf + i * 4096 + j * 256 + l15 * 16 + quad * 4) =
                make_uint2(pack2(acc[0], acc[1]), pack2(acc[2], acc[3]));
        };
        auto computeT = [&](int i, const TSet& s) {
            int td = tdesc[i];
            float wf = ((td >> 8) == (td & 255)) ? 1.0f : 2.0f;
            colT(i, wf, 2 * w,     s.p0, s.p1, s.p2, s.p3, s);
            colT(i, wf, 2 * w + 1, s.q0, s.q1, s.q2, s.q3, s);
        };

        TSet A, B;
        loadT(0, A);
        int i = 0;
#pragma unroll 1
        for (; i + 2 <= NT; i += 2) {
            loadT(i + 1, B);
            computeT(i, A);
            if (i + 2 < NT) loadT(i + 2, A);
            computeT(i + 1, B);
        }
        if (i < NT) computeT(i, A);   // NT odd tail (regs preloaded)

#pragma unroll
        for (int off = 1; off < 16; off <<= 1) {
#pragma unroll
            for (int r = 0; r < 4; r++) {
                lsum[r] += __shfl_xor(lsum[r], off);
                lssq[r] += __shfl_xor(lssq[r], off);
            }
        }
        if (l15 == 0) {
#pragma unroll
            for (int r = 0; r < 4; r++) {
                red[w][quad * 4 + r]      = lsum[r];
                red[w][16 + quad * 4 + r] = lssq[r];
            }
        }
        __syncthreads();
        if (tid < 32) {
            float v = 0.f;
#pragma unroll
            for (int k = 0; k < 8; k++) v += red[k][tid];
            atomicAdd(stats1 + rep32 + tid, v);
        }
    }
    gbar(flags, 1);

    // ---------------- phase 2: moments of d2; write act1 back in place ----
    {
        int pc = lane & 31, kh = lane >> 5;
        float sc[8], sh[8];
#pragma unroll
        for (int jc = 0; jc < 8; jc++) {
            int c = kh * 8 + jc;
            float S = 0.f, Q = 0.f;
#pragma unroll
            for (int rp = 0; rp < 16; rp++) {
                S += stats1[rp * 32 + c];
                Q += stats1[rp * 32 + 16 + c];
            }
            float mu  = S * INV_M;
            float var = fmaf(-mu, mu, Q * INV_M);
            float s   = g1[c] * rsqrtf(var + EPS);
            sc[jc] = s;
            sh[jc] = fmaf(-mu, s, be1[c]);
        }
        frag8 fw2; fw2.i = make_int4(0, 0, 0, 0);
        if (pc < 16) {
            const float* wp = W2 + pc * 16 + kh * 8;
            float4 wa = ld4(wp), wb = ld4(wp + 4);
            fw2.i = make_int4(pack2(wa.x, wa.y), pack2(wa.z, wa.w),
                              pack2(wb.x, wb.y), pack2(wb.z, wb.w));
        }
        f32x16 z;
#pragma unroll
        for (int r = 0; r < 16; r++) z[r] = 0.0f;
        float sum2[8], ssq2[8];
#pragma unroll
        for (int r = 0; r < 8; r++) { sum2[r] = 0.f; ssq2[r] = 0.f; }

        int base = w * 512 + pc * 16 + kh * 8;   // ushort offset in slot

        auto body2 = [&](int i, uint4 v) {
            int td = tdesc[i];
            float wf = ((td >> 8) == (td & 255)) ? 1.0f : 2.0f;
            float a0 = bflo(v.x), a1 = bfhi(v.x);
            float a2 = bflo(v.y), a3 = bfhi(v.y);
            float a4 = bflo(v.z), a5 = bfhi(v.z);
            float a6 = bflo(v.w), a7 = bfhi(v.w);
            a0 = lrelu(fmaf(a0, sc[0], sh[0]));
            a1 = lrelu(fmaf(a1, sc[1], sh[1]));
            a2 = lrelu(fmaf(a2, sc[2], sh[2]));
            a3 = lrelu(fmaf(a3, sc[3], sh[3]));
            a4 = lrelu(fmaf(a4, sc[4], sh[4]));
            a5 = lrelu(fmaf(a5, sc[5], sh[5]));
            a6 = lrelu(fmaf(a6, sc[6], sh[6]));
            a7 = lrelu(fmaf(a7, sc[7], sh[7]));
            frag8 fbv;
            fbv.i = make_int4(packtr(a0, a1), packtr(a2, a3),
                              packtr(a4, a5), packtr(a6, a7));
            *(uint4*)(hbuf + i * 4096 + base) =
                make_uint4(fbv.i.x, fbv.i.y, fbv.i.z, fbv.i.w);
            f32x16 d = __builtin_amdgcn_mfma_f32_32x32x16_bf16(fw2.v, fbv.v,
                                                               z, 0, 0, 0);
#pragma unroll
            for (int r = 0; r < 8; r++) {
                float dv = d[r];
                float wd = wf * dv;
                sum2[r] += wd;
                ssq2[r] = fmaf(wd, dv, ssq2[r]);
            }
        };

        uint4 v0 = *(const uint4*)(hbuf + base);
        uint4 v1 = *(const uint4*)(hbuf + 4096 + base);
        int i = 0;
#pragma unroll 1
        for (; i + 2 <= NT; i += 2) {
            uint4 n0 = v0, n1 = v1;
            if (i + 3 < NT) {
                n0 = *(const uint4*)(hbuf + (i + 2) * 4096 + base);
                n1 = *(const uint4*)(hbuf + (i + 3) * 4096 + base);
            } else if (i + 2 < NT) {
                n0 = *(const uint4*)(hbuf + (i + 2) * 4096 + base);
            }
            body2(i, v0);
            body2(i + 1, v1);
            v0 = n0; v1 = n1;
        }
        if (i < NT) body2(i, v0);

#pragma unroll
        for (int off = 1; off < 32; off <<= 1) {
#pragma unroll
            for (int r = 0; r < 8; r++) {
                sum2[r] += __shfl_xor(sum2[r], off);
                ssq2[r] += __shfl_xor(ssq2[r], off);
            }
        }
        if (pc == 0) {
#pragma unroll
            for (int r = 0; r < 8; r++) {
                int o = (r & 3) + 8 * (r >> 2) + 4 * kh;
                red[w][o]      = sum2[r];
                red[w][16 + o] = ssq2[r];
            }
        }
        __syncthreads();
        if (tid < 32) {
            float v = 0.f;
#pragma unroll
            for (int k = 0; k < 8; k++) v += red[k][tid];
            atomicAdd(raw2 + rep32 + tid, v);
        }
    }
    gbar(flags, 2);

    // ---------------- phase 3: act1 -> d2 -> act2 -> h3 (wave-private) ----
    {
        int pc = lane & 31, kh = lane >> 5;
        float sc2[8], sh2[8];
#pragma unroll
        for (int r = 0; r < 8; r++) {
            int c = (r & 3) + 8 * (r >> 2) + 4 * kh;
            float S = 0.f, Q = 0.f;
#pragma unroll
            for (int rp = 0; rp < 16; rp++) {
                S += raw2[rp * 32 + c];
                Q += raw2[rp * 32 + 16 + c];
            }
            float bc = b2[c];
            float sm = S + FNN * bc;
            float sq = Q + 2.0f * bc * S + FNN * bc * bc;
            float mu  = sm * INV_M;
            float var = fmaf(-mu, mu, sq * INV_M);
            float s   = g2[c] * rsqrtf(var + EPS);
            float shv = fmaf(-mu, s, be2[c]);
            sc2[r] = s;
            sh2[r] = fmaf(s, bc, shv);
        }
        frag8 fw2; fw2.i = make_int4(0, 0, 0, 0);
        if (pc < 16) {
            const float* wp = W2 + pc * 16 + kh * 8;
            float4 wa = ld4(wp), wb = ld4(wp + 4);
            fw2.i = make_int4(pack2(wa.x, wa.y), pack2(wa.z, wa.w),
                              pack2(wb.x, wb.y), pack2(wb.z, wb.w));
        }
        frag8 fw3; fw3.i = make_int4(0, 0, 0, 0);
        if (pc < 8) {
            const float* wp = W3 + pc * 16 + kh * 8;
            float4 wa = ld4(wp), wb = ld4(wp + 4);
            fw3.i = make_int4(pack2(wa.x, wa.y), pack2(wa.z, wa.w),
                              pack2(wb.x, wb.y), pack2(wb.z, wb.w));
        }
        float b3r[4];
#pragma unroll
        for (int r = 0; r < 4; r++) b3r[r] = b3[kh * 4 + r];
        f32x16 z;
#pragma unroll
        for (int r = 0; r < 16; r++) z[r] = 0.0f;
        float sum3[4] = {0.f, 0.f, 0.f, 0.f};
        float ssq3[4] = {0.f, 0.f, 0.f, 0.f};

        int rbase = w * 512 + pc * 16 + kh * 8;   // act1 read (ushorts)
        int wbase = w * 512 + pc * 8 + kh * 4;    // h3 write (ushorts)

        uint4 v = *(const uint4*)(hbuf + rbase);
#pragma unroll 1
        for (int i = 0; i < NT; i++) {
            uint4 vn = v;
            if (i + 1 < NT)
                vn = *(const uint4*)(hbuf + (i + 1) * 4096 + rbase);
            int td = tdesc[i];
            float wf = ((td >> 8) == (td & 255)) ? 1.0f : 2.0f;
            frag8 fbv;
            fbv.i = make_int4((int)v.x, (int)v.y, (int)v.z, (int)v.w);
            f32x16 d = __builtin_amdgcn_mfma_f32_32x32x16_bf16(fw2.v, fbv.v,
                                                               z, 0, 0, 0);
            float t0 = lrelu(fmaf(d[0], sc2[0], sh2[0]));
            float t1 = lrelu(fmaf(d[1], sc2[1], sh2[1]));
            float t2 = lrelu(fmaf(d[2], sc2[2], sh2[2]));
            float t3 = lrelu(fmaf(d[3], sc2[3], sh2[3]));
            float t4 = lrelu(fmaf(d[4], sc2[4], sh2[4]));
            float t5 = lrelu(fmaf(d[5], sc2[5], sh2[5]));
            float t6 = lrelu(fmaf(d[6], sc2[6], sh2[6]));
            float t7 = lrelu(fmaf(d[7], sc2[7], sh2[7]));
            unsigned e0 = packtr(t0, t1), e1 = packtr(t2, t3);
            unsigned e2 = packtr(t4, t5), e3 = packtr(t6, t7);
            unsigned p0 = kh ? e0 : e2;
            unsigned p1 = kh ? e1 : e3;
            unsigned q0 = shflx32(p0);
            unsigned q1 = shflx32(p1);
            frag8 fb2;
            fb2.i = make_int4(kh ? q0 : e0, kh ? q1 : e1,
                              kh ? e2 : q0, kh ? e3 : q1);
            f32x16 d2 = __builtin_amdgcn_mfma_f32_32x32x16_bf16(fw3.v, fb2.v,
                                                                z, 0, 0, 0);
            float h0  = d2[0] + b3r[0];
            float h1v = d2[1] + b3r[1];
            float h2v = d2[2] + b3r[2];
            float h3v = d2[3] + b3r[3];
            float wh;
            wh = wf * h0;  sum3[0] += wh; ssq3[0] = fmaf(wh, h0,  ssq3[0]);
            wh = wf * h1v; sum3[1] += wh; ssq3[1] = fmaf(wh, h1v, ssq3[1]);
            wh = wf * h2v; sum3[2] += wh; ssq3[2] = fmaf(wh, h2v, ssq3[2]);
            wh = wf * h3v; sum3[3] += wh; ssq3[3] = fmaf(wh, h3v, ssq3[3]);
            *(uint2*)(hbuf + i * 4096 + wbase) =
                make_uint2(pack2(h0, h1v), pack2(h2v, h3v));
            v = vn;
        }
#pragma unroll
        for (int off = 1; off < 32; off <<= 1) {
#pragma unroll
            for (int r = 0; r < 4; r++) {
                sum3[r] += __shfl_xor(sum3[r], off);
                ssq3[r] += __shfl_xor(ssq3[r], off);
            }
        }
        if (pc == 0) {
#pragma unroll
            for (int r = 0; r < 4; r++) {
                red[w][kh * 4 + r]     = sum3[r];
                red[w][8 + kh * 4 + r] = ssq3[r];
            }
        }
        __syncthreads();
        if (tid < 16) {
            float v2 = 0.f;
#pragma unroll
            for (int k = 0; k < 8; k++) v2 += red[k][tid];
            atomicAdd(stats3 + rep16 + tid, v2);
        }
    }
    gbar(flags, 3);

    // ---------------- phase 4: moments of h4; write act3 back in place ----
    {
        float sc3[8], sh3[8];
        bn8_inline(stats3, g3, be3, sc3, sh3);
        int h = tid >> 8;          // half: tiles i ≡ h (mod 2)
        int p = tid & 255;
        int pbase = (p >> 5) * 512 + (p & 31) * 8;   // ushort offset in slot

        float w4r[8][8], bi[8];
#pragma unroll
        for (int o = 0; o < 8; o++) {
            const float* wr = W4 + o * 8;
            float4 v0 = ld4(wr);
            float4 v1 = ld4(wr + 4);
            w4r[o][0] = v0.x; w4r[o][1] = v0.y;
            w4r[o][2] = v0.z; w4r[o][3] = v0.w;
            w4r[o][4] = v1.x; w4r[o][5] = v1.y;
            w4r[o][6] = v1.z; w4r[o][7] = v1.w;
            bi[o] = b4[o];
        }
        float sum4[8], ssq4[8];
#pragma unroll
        for (int o = 0; o < 8; o++) { sum4[o] = 0.f; ssq4[o] = 0.f; }

        uint4 v = *(const uint4*)(hbuf + h * 4096 + pbase);
#pragma unroll 1
        for (int i = h; i < NT; i += 2) {
            uint4 vn = v;
            if (i + 2 < NT)
                vn = *(const uint4*)(hbuf + (i + 2) * 4096 + pbase);
            int td = tdesc[i];
            float wf = ((td >> 8) == (td & 255)) ? 1.0f : 2.0f;
            float a0 = bflo(v.x), a1 = bfhi(v.x);
            float a2 = bflo(v.y), a3 = bfhi(v.y);
            float a4 = bflo(v.z), a5 = bfhi(v.z);
            float a6 = bflo(v.w), a7 = bfhi(v.w);
            a0 = lrelu(fmaf(a0, sc3[0], sh3[0]));
            a1 = lrelu(fmaf(a1, sc3[1], sh3[1]));
            a2 = lrelu(fmaf(a2, sc3[2], sh3[2]));
            a3 = lrelu(fmaf(a3, sc3[3], sh3[3]));
            a4 = lrelu(fmaf(a4, sc3[4], sh3[4]));
            a5 = lrelu(fmaf(a5, sc3[5], sh3[5]));
            a6 = lrelu(fmaf(a6, sc3[6], sh3[6]));
            a7 = lrelu(fmaf(a7, sc3[7], sh3[7]));
            uint4 pk = make_uint4(pack2(a0, a1), pack2(a2, a3),
                                  pack2(a4, a5), pack2(a6, a7));
            *(uint4*)(hbuf + i * 4096 + pbase) = pk;   // act3 write-back
            float r[8];
            r[0] = bflo(pk.x); r[1] = bfhi(pk.x);
            r[2] = bflo(pk.y); r[3] = bfhi(pk.y);
            r[4] = bflo(pk.z); r[5] = bfhi(pk.z);
            r[6] = bflo(pk.w); r[7] = bfhi(pk.w);
            float d[8];
#pragma unroll
            for (int o = 0; o < 8; o++) d[o] = bi[o];
#pragma unroll
            for (int c = 0; c < 8; c++) {
#pragma unroll
                for (int o = 0; o < 8; o++)
                    d[o] = fmaf(r[c], w4r[o][c], d[o]);
            }
#pragma unroll
            for (int o = 0; o < 8; o++) {
                float wd = wf * d[o];
                sum4[o] += wd;
                ssq4[o] = fmaf(wd, d[o], ssq4[o]);
            }
            v = vn;
        }
#pragma unroll
        for (int off = 1; off < 64; off <<= 1) {
#pragma unroll
            for (int o = 0; o < 8; o++) {
                sum4[o] += __shfl_xor(sum4[o], off);
                ssq4[o] += __shfl_xor(ssq4[o], off);
            }
        }
        if (lane == 0) {
#pragma unroll
            for (int o = 0; o < 8; o++) {
                red[w][o]     = sum4[o];
                red[w][8 + o] = ssq4[o];
            }
        }
        __syncthreads();
        if (tid < 16) {
            float v2 = 0.f;
#pragma unroll
            for (int k = 0; k < 8; k++) v2 += red[k][tid];
            atomicAdd(stats4 + rep16 + tid, v2);
        }
    }
    gbar(flags, 4);

    // ---------------- phase 5: out tile + LDS-transposed mirror -----------
    {
        float w4f[8][8], b4f[8], w5r[8];
#pragma unroll
        for (int o = 0; o < 8; o++) {
            float S = 0.f, Q = 0.f;
#pragma unroll
            for (int rp = 0; rp < 16; rp++) {
                S += stats4[rp * 16 + o];
                Q += stats4[rp * 16 + 8 + o];
            }
            float mu  = S * INV_M;
            float var = fmaf(-mu, mu, Q * INV_M);
            float s   = g4[o] * rsqrtf(var + EPS);
            float shv = fmaf(-mu, s, be4[o]);
            b4f[o] = fmaf(s, b4[o], shv);
            const float* wr = W4 + o * 8;
            float4 v0 = ld4(wr);
            float4 v1 = ld4(wr + 4);
            w4f[o][0] = s * v0.x; w4f[o][1] = s * v0.y;
            w4f[o][2] = s * v0.z; w4f[o][3] = s * v0.w;
            w4f[o][4] = s * v1.x; w4f[o][5] = s * v1.y;
            w4f[o][6] = s * v1.z; w4f[o][7] = s * v1.w;
            w5r[o] = W5[o];
        }
        float b5v = b5[0];
        int half = tid >> 8;
        int lt   = tid & 255;
        int nl = lt >> 4, ml = lt & 15;
        int pbase = (lt >> 5) * 512 + (lt & 31) * 8;
        int npair = (NT + 1) >> 1;
        int buf = 0;

#pragma unroll 1
        for (int jp = 0; jp < npair; jp++) {
            int i = 2 * jp + half;
            bool act = (i < NT);
            int mt = 0, nc = 0;
            if (act) {
                int td = tdesc[i];
                mt = td >> 8; nc = td & 255;
                uint4 v = *(const uint4*)(hbuf + i * 4096 + pbase);
                float a[8];   // act3, already BN3+lrelu'd
                a[0] = bflo(v.x); a[1] = bfhi(v.x);
                a[2] = bflo(v.y); a[3] = bfhi(v.y);
                a[4] = bflo(v.z); a[5] = bfhi(v.z);
                a[6] = bflo(v.w); a[7] = bfhi(v.w);
                float accv = b5v;
#pragma unroll
                for (int o = 0; o < 8; o++) {
                    float hh = b4f[o];
#pragma unroll
                    for (int c = 0; c < 8; c++)
                        hh = fmaf(a[c], w4f[o][c], hh);
                    accv = fmaf(lrelu(hh), w5r[o], accv);
                }
                out[(size_t)(nc * 16 + nl) * NPTS + mt * 16 + ml] = accv;
                Tm[buf][half][nl * 17 + ml] = accv;
            }
            __syncthreads();
            if (act) {
                float mv = Tm[buf][half][ml * 17 + nl];
                out[(size_t)(mt * 16 + nl) * NPTS + nc * 16 + ml] = mv;
            }
            buf ^= 1;
        }
    }
}

// --------------------------------------------------------------------------
extern "C" void kernel_launch(void* const* d_in, const int* in_sizes, int n_in,
                              void* d_out, int out_size, void* d_ws,
                              size_t ws_size, hipStream_t stream) {
    const float* x   = (const float*)d_in[0];
    const float* W1  = (const float*)d_in[1];
    const float* b1  = (const float*)d_in[2];
    const float* g1  = (const float*)d_in[3];
    const float* be1 = (const float*)d_in[4];
    const float* W2  = (const float*)d_in[5];
    const float* b2  = (const float*)d_in[6];
    const float* g2  = (const float*)d_in[7];
    const float* be2 = (const float*)d_in[8];
    const float* W3  = (const float*)d_in[9];
    const float* b3  = (const float*)d_in[10];
    const float* g3  = (const float*)d_in[11];
    const float* be3 = (const float*)d_in[12];
    const float* W4  = (const float*)d_in[13];
    const float* b4  = (const float*)d_in[14];
    const float* g4  = (const float*)d_in[15];
    const float* be4 = (const float*)d_in[16];
    const float* W5  = (const float*)d_in[17];
    const float* b5  = (const float*)d_in[18];

    float* ws   = (float*)d_ws;
    float* outp = (float*)d_out;

    k_prep<<<22, 256, 0, stream>>>(ws);
    k_mega<<<NBLK, 512, 0, stream>>>(
        x, W1, b1, g1, be1, W2, b2, g2, be2, W3, b3, g3, be3,
        W4, b4, g4, be4, W5, b5, outp, ws);
}

// Round 6
// 174.322 us; speedup vs baseline: 1.4511x; 1.3310x over previous
//
#include <hip/hip_runtime.h>
#include <stdint.h>

// ---------------------------------------------------------------------------
// AdjCompute R18: R17 with the grid-barrier made FENCE-FREE and per-iteration
// tdesc LDS reads removed:
//   - barrier: relaxed agent-scope flag store preceded by explicit
//     s_waitcnt vmcnt(0) (orders wave-0's stats atomicAdds; no cache
//     maintenance). NO __threadfence anywhere.
//   - after each barrier, stats are staged into an LDS mirror via
//     agent-scope relaxed ATOMIC loads (bypass stale L1/L2, read LLC --
//     same primitive as the proven flag poll). BN math reads LDS.
//   - diagmask: wf for phases 2/3/4 comes from a ballot-built 32-bit mask
//     in registers (kills the per-iteration tdesc ds_read + lgkmcnt drain).
// Everything else identical to R17 (512 thr, TSet prefetch, 16-replica
// stats, in-place act1/act3 write-back).
//
// LDS: hbuf 155648 + red 1024 + Tm 4352 + tdesc 80 + sstat 2048
//    = 163152 B <= 163840, 1 block/CU.
//
// ws layout (floats), zeroed by k_prep [0..5632):
//   [0..512)     stats1  16 x (sum16|ssq16)  stride 32
//   [512..1024)  raw2    16 x (S16|Q16)      stride 32
//   [1024..1280) stats3  16 x (sum8|ssq8)    stride 16
//   [1280..1536) stats4  16 x (sum8|ssq8)    stride 16
//   [1536..5632) flags: 256 blocks x 16 ints (64B spacing), epoch counters
//
// Slot layout (8192 B per tile):
//   phase1 h1 / phase2 act1 : pos p, ch c at byte p*32 + c*2
//   phase3 h3 / phase4 act3 : pos p, ch c at byte (p>>5)*1024+(p&31)*16+c*2
// ---------------------------------------------------------------------------

#define NPTS 1536
#define NTILES 4656
#define NBLK 256
#define NTMAX 19
static constexpr float FNN   = 2359296.0f;
static constexpr float EPS   = 1e-5f;
static constexpr float SLOPE = 0.01f;
static constexpr float INV_M = 1.0f / 2359296.0f;

typedef __attribute__((ext_vector_type(8)))  short bf16x8;
typedef __attribute__((ext_vector_type(4)))  float f32x4;
typedef __attribute__((ext_vector_type(16))) float f32x16;
union frag8 { int4 i; bf16x8 v; };

__device__ __forceinline__ float bflo(unsigned u) {
    return __builtin_bit_cast(float, u << 16);
}
__device__ __forceinline__ float bfhi(unsigned u) {
    return __builtin_bit_cast(float, u & 0xffff0000u);
}
__device__ __forceinline__ unsigned short f2bf(float f) {   // RNE
    unsigned u = __builtin_bit_cast(unsigned, f);
    u += 0x7fffu + ((u >> 16) & 1u);
    return (unsigned short)(u >> 16);
}
__device__ __forceinline__ unsigned pack2(float lo, float hi) {  // RNE pair
    return (unsigned)f2bf(lo) | ((unsigned)f2bf(hi) << 16);
}
__device__ __forceinline__ unsigned packtr(float lo, float hi) { // trunc
    unsigned a = __builtin_bit_cast(unsigned, lo);
    unsigned b = __builtin_bit_cast(unsigned, hi);
#if __has_builtin(__builtin_amdgcn_perm)
    return __builtin_amdgcn_perm(b, a, 0x07060302u);
#else
    return (a >> 16) | (b & 0xffff0000u);
#endif
}
__device__ __forceinline__ float lrelu(float t) {
    return fmaxf(t, t * SLOPE);
}
__device__ __forceinline__ float4 ld4(const float* p) {
    return *(const float4*)p;
}
__device__ __forceinline__ unsigned shflx32(unsigned v) {
    return (unsigned)__shfl_xor((int)v, 32);
}
__device__ __forceinline__ float aload(const float* p) {
    int vi = __hip_atomic_load((const int*)p, __ATOMIC_RELAXED,
                               __HIP_MEMORY_SCOPE_AGENT);
    return __builtin_bit_cast(float, vi);
}

// fence-free grid barrier:
//   arrive:  thread 0: s_waitcnt vmcnt(0) (drain wave-0's stats atomicAdds,
//            the only cross-block writes) + relaxed agent flag store
//   wait:    threads 0..255 poll one flag each (relaxed agent loads -- these
//            are serviced at the LLC, so no cache invalidate is needed for
//            them or for the atomic staging loads that follow)
__device__ __forceinline__ void gbar(int* flags, int epoch) {
    __syncthreads();
    if (threadIdx.x == 0) {
        asm volatile("s_waitcnt vmcnt(0)" ::: "memory");
        __hip_atomic_store(flags + (int)blockIdx.x * 16, epoch,
                           __ATOMIC_RELAXED, __HIP_MEMORY_SCOPE_AGENT);
    }
    if (threadIdx.x < 256) {
        const int* f = flags + (int)threadIdx.x * 16;
        while (__hip_atomic_load(f, __ATOMIC_RELAXED,
                                 __HIP_MEMORY_SCOPE_AGENT) < epoch) {
            __builtin_amdgcn_s_sleep(2);
        }
    }
    __syncthreads();
}

// triangle tile decode: t -> (mt, nc), 0<=mt<=nc<96, row-major in mt.
__device__ __forceinline__ int2 tri_decode(int t) {
    float disc = 37249.0f - 8.0f * (float)t;    // 193^2 - 8t
    int mt = (int)((193.0f - sqrtf(disc)) * 0.5f);
    if (mt < 0) mt = 0;
    if (mt > 95) mt = 95;
    while (96 * (mt + 1) - ((mt + 1) * mt) / 2 <= t) mt++;
    while (96 * mt - (mt * (mt - 1)) / 2 > t) mt--;
    int nc = mt + (t - (96 * mt - (mt * (mt - 1)) / 2));
    return make_int2(mt, nc);
}

// bn over 8 channels from 16-replica 8ch stats in LDS (replica stride 16)
__device__ __forceinline__ void bn8_inline(
        const float* stats, const float* __restrict__ g,
        const float* __restrict__ be, float* sc, float* sh) {
#pragma unroll
    for (int c = 0; c < 8; c++) {
        float S = 0.f, Q = 0.f;
#pragma unroll
        for (int rp = 0; rp < 16; rp++) {
            S += stats[rp * 16 + c];
            Q += stats[rp * 16 + 8 + c];
        }
        float mu  = S * INV_M;
        float var = fmaf(-mu, mu, Q * INV_M);
        float s   = g[c] * rsqrtf(var + EPS);
        sc[c] = s;
        sh[c] = fmaf(-mu, s, be[c]);
    }
}

// --------------------------------------------------------------------------
__global__ __launch_bounds__(256) void k_prep(float* __restrict__ ws) {
    int t = blockIdx.x * 256 + threadIdx.x;
    if (t < 5632) ws[t] = 0.0f;
}

// --------------------------------------------------------------------------
struct TSet {
    float4 a0, a1, a2, a3;   // xa rows (mt*16 + l15)
    float4 p0, p1, p2, p3;   // u col 2w
    float4 q0, q1, q2, q3;   // u col 2w+1
};

__global__ __launch_bounds__(512, 2) void k_mega(
        const float* __restrict__ x,
        const float* __restrict__ W1, const float* __restrict__ b1,
        const float* __restrict__ g1, const float* __restrict__ be1,
        const float* __restrict__ W2, const float* __restrict__ b2,
        const float* __restrict__ g2, const float* __restrict__ be2,
        const float* __restrict__ W3, const float* __restrict__ b3,
        const float* __restrict__ g3, const float* __restrict__ be3,
        const float* __restrict__ W4, const float* __restrict__ b4,
        const float* __restrict__ g4, const float* __restrict__ be4,
        const float* __restrict__ W5, const float* __restrict__ b5,
        float* __restrict__ out, float* __restrict__ ws) {

    __shared__ unsigned short hbuf[NTMAX * 4096];  // 19 slots * 8192 B
    __shared__ float red[8][32];
    __shared__ float Tm[2][2][272];                // [buf][half][nl*17+ml]
    __shared__ int tdesc[NTMAX + 1];               // [NTMAX] = diagmask
    __shared__ float sstat[512];                   // staged stats mirror

    int tid  = threadIdx.x;
    int bid  = blockIdx.x;
    int w    = tid >> 6;
    int lane = tid & 63;
    int NT   = 18 + (bid < 48 ? 1 : 0);

    float* stats1 = ws;
    float* raw2   = ws + 512;
    float* stats3 = ws + 1024;
    float* stats4 = ws + 1280;
    int* flags    = (int*)(ws + 1536);
    int rep32 = (bid & 15) * 32;
    int rep16 = (bid & 15) * 16;

    if (tid < NT) {
        int2 tc = tri_decode(bid + NBLK * tid);
        tdesc[tid] = (tc.x << 8) | tc.y;
    }
    __syncthreads();
    if (w == 0) {
        bool dg = false;
        if (lane < NT) {
            int td = tdesc[lane];
            dg = (td >> 8) == (td & 255);
        }
        unsigned long long m = __ballot(dg);
        if (lane == 0) tdesc[NTMAX] = (int)(unsigned)m;
    }
    __syncthreads();
    unsigned diagmask = (unsigned)tdesc[NTMAX];

    // ---------------- phase 1: h1 -> LDS + weighted stats1 ----------------
    {
        int l15 = lane & 15, quad = lane >> 4, cb = quad * 8;
        const float* wr = W1 + l15 * 64 + cb;
        float4 w0 = ld4(wr);
        float4 w1v = ld4(wr + 4);
        float4 w2v = ld4(wr + 32);
        float4 w3v = ld4(wr + 36);
        frag8 fb1, fb2;
        fb1.i = make_int4(pack2(w0.x, w0.y), pack2(w0.z, w0.w),
                          pack2(w1v.x, w1v.y), pack2(w1v.z, w1v.w));
        fb2.i = make_int4(pack2(w2v.x, w2v.y), pack2(w2v.z, w2v.w),
                          pack2(w3v.x, w3v.y), pack2(w3v.z, w3v.w));
        float4 b1v = ld4(b1 + quad * 4);
        float lsum[4] = {0.f, 0.f, 0.f, 0.f};
        float lssq[4] = {0.f, 0.f, 0.f, 0.f};

        auto loadT = [&](int i, TSet& s) {
            int td = tdesc[i];
            int mt = td >> 8, nc = td & 255;
            const float* xr = x + (mt * 16 + l15) * 64 + cb;
            s.a0 = ld4(xr); s.a1 = ld4(xr + 4);
            s.a2 = ld4(xr + 32); s.a3 = ld4(xr + 36);
            const float* pA = x + (size_t)(nc * 16 + 2 * w) * 64 + cb;
            s.p0 = ld4(pA); s.p1 = ld4(pA + 4);
            s.p2 = ld4(pA + 32); s.p3 = ld4(pA + 36);
            const float* pB = x + (size_t)(nc * 16 + 2 * w + 1) * 64 + cb;
            s.q0 = ld4(pB); s.q1 = ld4(pB + 4);
            s.q2 = ld4(pB + 32); s.q3 = ld4(pB + 36);
        };
        auto colT = [&](int i, float wf, int j, float4 u0, float4 u1,
                        float4 u2, float4 u3, const TSet& s) {
            frag8 fa1, fa2;
            fa1.i = make_int4(
                packtr(fabsf(s.a0.x - u0.x), fabsf(s.a0.y - u0.y)),
                packtr(fabsf(s.a0.z - u0.z), fabsf(s.a0.w - u0.w)),
                packtr(fabsf(s.a1.x - u1.x), fabsf(s.a1.y - u1.y)),
                packtr(fabsf(s.a1.z - u1.z), fabsf(s.a1.w - u1.w)));
            fa2.i = make_int4(
                packtr(fabsf(s.a2.x - u2.x), fabsf(s.a2.y - u2.y)),
                packtr(fabsf(s.a2.z - u2.z), fabsf(s.a2.w - u2.w)),
                packtr(fabsf(s.a3.x - u3.x), fabsf(s.a3.y - u3.y)),
                packtr(fabsf(s.a3.z - u3.z), fabsf(s.a3.w - u3.w)));
            f32x4 acc = {b1v.x, b1v.y, b1v.z, b1v.w};
            acc = __builtin_amdgcn_mfma_f32_16x16x32_bf16(fb1.v, fa1.v,
                                                          acc, 0, 0, 0);
            acc = __builtin_amdgcn_mfma_f32_16x16x32_bf16(fb2.v, fa2.v,
                                                          acc, 0, 0, 0);
#pragma unroll
            for (int r = 0; r < 4; r++) {
                float wa = wf * acc[r];
                lsum[r] += wa;
                lssq[r] = fmaf(wa, acc[r], lssq[r]);
            }
            *(uint2*)(hbuf + i * 4096 + j * 256 + l15 * 16 + quad * 4) =
                make_uint2(pack2(acc[0], acc[1]), pack2(acc[2], acc[3]));
        };
        auto computeT = [&](int i, const TSet& s) {
            float wf = ((diagmask >> i) & 1u) ? 1.0f : 2.0f;
            colT(i, wf, 2 * w,     s.p0, s.p1, s.p2, s.p3, s);
            colT(i, wf, 2 * w + 1, s.q0, s.q1, s.q2, s.q3, s);
        };

        TSet A, B;
        loadT(0, A);
        int i = 0;
#pragma unroll 1
        for (; i + 2 <= NT; i += 2) {
            loadT(i + 1, B);
            computeT(i, A);
            if (i + 2 < NT) loadT(i + 2, A);
            computeT(i + 1, B);
        }
        if (i < NT) computeT(i, A);   // NT odd tail (regs preloaded)

#pragma unroll
        for (int off = 1; off < 16; off <<= 1) {
#pragma unroll
            for (int r = 0; r < 4; r++) {
                lsum[r] += __shfl_xor(lsum[r], off);
                lssq[r] += __shfl_xor(lssq[r], off);
            }
        }
        if (l15 == 0) {
#pragma unroll
            for (int r = 0; r < 4; r++) {
                red[w][quad * 4 + r]      = lsum[r];
                red[w][16 + quad * 4 + r] = lssq[r];
            }
        }
        __syncthreads();
        if (tid < 32) {
            float v = 0.f;
#pragma unroll
            for (int k = 0; k < 8; k++) v += red[k][tid];
            atomicAdd(stats1 + rep32 + tid, v);
        }
    }
    gbar(flags, 1);
    sstat[tid] = aload(stats1 + tid);        // stage 512 floats via LLC
    __syncthreads();

    // ---------------- phase 2: moments of d2; write act1 back in place ----
    {
        int pc = lane & 31, kh = lane >> 5;
        float sc[8], sh[8];
#pragma unroll
        for (int jc = 0; jc < 8; jc++) {
            int c = kh * 8 + jc;
            float S = 0.f, Q = 0.f;
#pragma unroll
            for (int rp = 0; rp < 16; rp++) {
                S += sstat[rp * 32 + c];
                Q += sstat[rp * 32 + 16 + c];
            }
            float mu  = S * INV_M;
            float var = fmaf(-mu, mu, Q * INV_M);
            float s   = g1[c] * rsqrtf(var + EPS);
            sc[jc] = s;
            sh[jc] = fmaf(-mu, s, be1[c]);
        }
        frag8 fw2; fw2.i = make_int4(0, 0, 0, 0);
        if (pc < 16) {
            const float* wp = W2 + pc * 16 + kh * 8;
            float4 wa = ld4(wp), wb = ld4(wp + 4);
            fw2.i = make_int4(pack2(wa.x, wa.y), pack2(wa.z, wa.w),
                              pack2(wb.x, wb.y), pack2(wb.z, wb.w));
        }
        f32x16 z;
#pragma unroll
        for (int r = 0; r < 16; r++) z[r] = 0.0f;
        float sum2[8], ssq2[8];
#pragma unroll
        for (int r = 0; r < 8; r++) { sum2[r] = 0.f; ssq2[r] = 0.f; }

        int base = w * 512 + pc * 16 + kh * 8;   // ushort offset in slot

        auto body2 = [&](int i, uint4 v) {
            float wf = ((diagmask >> i) & 1u) ? 1.0f : 2.0f;
            float a0 = bflo(v.x), a1 = bfhi(v.x);
            float a2 = bflo(v.y), a3 = bfhi(v.y);
            float a4 = bflo(v.z), a5 = bfhi(v.z);
            float a6 = bflo(v.w), a7 = bfhi(v.w);
            a0 = lrelu(fmaf(a0, sc[0], sh[0]));
            a1 = lrelu(fmaf(a1, sc[1], sh[1]));
            a2 = lrelu(fmaf(a2, sc[2], sh[2]));
            a3 = lrelu(fmaf(a3, sc[3], sh[3]));
            a4 = lrelu(fmaf(a4, sc[4], sh[4]));
            a5 = lrelu(fmaf(a5, sc[5], sh[5]));
            a6 = lrelu(fmaf(a6, sc[6], sh[6]));
            a7 = lrelu(fmaf(a7, sc[7], sh[7]));
            frag8 fbv;
            fbv.i = make_int4(packtr(a0, a1), packtr(a2, a3),
                              packtr(a4, a5), packtr(a6, a7));
            *(uint4*)(hbuf + i * 4096 + base) =
                make_uint4(fbv.i.x, fbv.i.y, fbv.i.z, fbv.i.w);
            f32x16 d = __builtin_amdgcn_mfma_f32_32x32x16_bf16(fw2.v, fbv.v,
                                                               z, 0, 0, 0);
#pragma unroll
            for (int r = 0; r < 8; r++) {
                float dv = d[r];
                float wd = wf * dv;
                sum2[r] += wd;
                ssq2[r] = fmaf(wd, dv, ssq2[r]);
            }
        };

        uint4 v0 = *(const uint4*)(hbuf + base);
        uint4 v1 = *(const uint4*)(hbuf + 4096 + base);
        int i = 0;
#pragma unroll 1
        for (; i + 2 <= NT; i += 2) {
            uint4 n0 = v0, n1 = v1;
            if (i + 3 < NT) {
                n0 = *(const uint4*)(hbuf + (i + 2) * 4096 + base);
                n1 = *(const uint4*)(hbuf + (i + 3) * 4096 + base);
            } else if (i + 2 < NT) {
                n0 = *(const uint4*)(hbuf + (i + 2) * 4096 + base);
            }
            body2(i, v0);
            body2(i + 1, v1);
            v0 = n0; v1 = n1;
        }
        if (i < NT) body2(i, v0);

#pragma unroll
        for (int off = 1; off < 32; off <<= 1) {
#pragma unroll
            for (int r = 0; r < 8; r++) {
                sum2[r] += __shfl_xor(sum2[r], off);
                ssq2[r] += __shfl_xor(ssq2[r], off);
            }
        }
        if (pc == 0) {
#pragma unroll
            for (int r = 0; r < 8; r++) {
                int o = (r & 3) + 8 * (r >> 2) + 4 * kh;
                red[w][o]      = sum2[r];
                red[w][16 + o] = ssq2[r];
            }
        }
        __syncthreads();
        if (tid < 32) {
            float v = 0.f;
#pragma unroll
            for (int k = 0; k < 8; k++) v += red[k][tid];
            atomicAdd(raw2 + rep32 + tid, v);
        }
    }
    gbar(flags, 2);
    sstat[tid] = aload(raw2 + tid);
    __syncthreads();

    // ---------------- phase 3: act1 -> d2 -> act2 -> h3 (wave-private) ----
    {
        int pc = lane & 31, kh = lane >> 5;
        float sc2[8], sh2[8];
#pragma unroll
        for (int r = 0; r < 8; r++) {
            int c = (r & 3) + 8 * (r >> 2) + 4 * kh;
            float S = 0.f, Q = 0.f;
#pragma unroll
            for (int rp = 0; rp < 16; rp++) {
                S += sstat[rp * 32 + c];
                Q += sstat[rp * 32 + 16 + c];
            }
            float bc = b2[c];
            float sm = S + FNN * bc;
            float sq = Q + 2.0f * bc * S + FNN * bc * bc;
            float mu  = sm * INV_M;
            float var = fmaf(-mu, mu, sq * INV_M);
            float s   = g2[c] * rsqrtf(var + EPS);
            float shv = fmaf(-mu, s, be2[c]);
            sc2[r] = s;
            sh2[r] = fmaf(s, bc, shv);
        }
        frag8 fw2; fw2.i = make_int4(0, 0, 0, 0);
        if (pc < 16) {
            const float* wp = W2 + pc * 16 + kh * 8;
            float4 wa = ld4(wp), wb = ld4(wp + 4);
            fw2.i = make_int4(pack2(wa.x, wa.y), pack2(wa.z, wa.w),
                              pack2(wb.x, wb.y), pack2(wb.z, wb.w));
        }
        frag8 fw3; fw3.i = make_int4(0, 0, 0, 0);
        if (pc < 8) {
            const float* wp = W3 + pc * 16 + kh * 8;
            float4 wa = ld4(wp), wb = ld4(wp + 4);
            fw3.i = make_int4(pack2(wa.x, wa.y), pack2(wa.z, wa.w),
                              pack2(wb.x, wb.y), pack2(wb.z, wb.w));
        }
        float b3r[4];
#pragma unroll
        for (int r = 0; r < 4; r++) b3r[r] = b3[kh * 4 + r];
        f32x16 z;
#pragma unroll
        for (int r = 0; r < 16; r++) z[r] = 0.0f;
        float sum3[4] = {0.f, 0.f, 0.f, 0.f};
        float ssq3[4] = {0.f, 0.f, 0.f, 0.f};

        int rbase = w * 512 + pc * 16 + kh * 8;   // act1 read (ushorts)
        int wbase = w * 512 + pc * 8 + kh * 4;    // h3 write (ushorts)

        uint4 v = *(const uint4*)(hbuf + rbase);
#pragma unroll 1
        for (int i = 0; i < NT; i++) {
            uint4 vn = v;
            if (i + 1 < NT)
                vn = *(const uint4*)(hbuf + (i + 1) * 4096 + rbase);
            float wf = ((diagmask >> i) & 1u) ? 1.0f : 2.0f;
            frag8 fbv;
            fbv.i = make_int4((int)v.x, (int)v.y, (int)v.z, (int)v.w);
            f32x16 d = __builtin_amdgcn_mfma_f32_32x32x16_bf16(fw2.v, fbv.v,
                                                               z, 0, 0, 0);
            float t0 = lrelu(fmaf(d[0], sc2[0], sh2[0]));
            float t1 = lrelu(fmaf(d[1], sc2[1], sh2[1]));
            float t2 = lrelu(fmaf(d[2], sc2[2], sh2[2]));
            float t3 = lrelu(fmaf(d[3], sc2[3], sh2[3]));
            float t4 = lrelu(fmaf(d[4], sc2[4], sh2[4]));
            float t5 = lrelu(fmaf(d[5], sc2[5], sh2[5]));
            float t6 = lrelu(fmaf(d[6], sc2[6], sh2[6]));
            float t7 = lrelu(fmaf(d[7], sc2[7], sh2[7]));
            unsigned e0 = packtr(t0, t1), e1 = packtr(t2, t3);
            unsigned e2 = packtr(t4, t5), e3 = packtr(t6, t7);
            unsigned p0 = kh ? e0 : e2;
            unsigned p1 = kh ? e1 : e3;
            unsigned q0 = shflx32(p0);
            unsigned q1 = shflx32(p1);
            frag8 fb2;
            fb2.i = make_int4(kh ? q0 : e0, kh ? q1 : e1,
                              kh ? e2 : q0, kh ? e3 : q1);
            f32x16 d2 = __builtin_amdgcn_mfma_f32_32x32x16_bf16(fw3.v, fb2.v,
                                                                z, 0, 0, 0);
            float h0  = d2[0] + b3r[0];
            float h1v = d2[1] + b3r[1];
            float h2v = d2[2] + b3r[2];
            float h3v = d2[3] + b3r[3];
            float wh;
            wh = wf * h0;  sum3[0] += wh; ssq3[0] = fmaf(wh, h0,  ssq3[0]);
            wh = wf * h1v; sum3[1] += wh; ssq3[1] = fmaf(wh, h1v, ssq3[1]);
            wh = wf * h2v; sum3[2] += wh; ssq3[2] = fmaf(wh, h2v, ssq3[2]);
            wh = wf * h3v; sum3[3] += wh; ssq3[3] = fmaf(wh, h3v, ssq3[3]);
            *(uint2*)(hbuf + i * 4096 + wbase) =
                make_uint2(pack2(h0, h1v), pack2(h2v, h3v));
            v = vn;
        }
#pragma unroll
        for (int off = 1; off < 32; off <<= 1) {
#pragma unroll
            for (int r = 0; r < 4; r++) {
                sum3[r] += __shfl_xor(sum3[r], off);
                ssq3[r] += __shfl_xor(ssq3[r], off);
            }
        }
        if (pc == 0) {
#pragma unroll
            for (int r = 0; r < 4; r++) {
                red[w][kh * 4 + r]     = sum3[r];
                red[w][8 + kh * 4 + r] = ssq3[r];
            }
        }
        __syncthreads();
        if (tid < 16) {
            float v2 = 0.f;
#pragma unroll
            for (int k = 0; k < 8; k++) v2 += red[k][tid];
            atomicAdd(stats3 + rep16 + tid, v2);
        }
    }
    gbar(flags, 3);
    if (tid < 256) sstat[tid] = aload(stats3 + tid);
    __syncthreads();

    // ---------------- phase 4: moments of h4; write act3 back in place ----
    {
        float sc3[8], sh3[8];
        bn8_inline(sstat, g3, be3, sc3, sh3);
        int h = tid >> 8;          // half: tiles i ≡ h (mod 2)
        int p = tid & 255;
        int pbase = (p >> 5) * 512 + (p & 31) * 8;   // ushort offset in slot

        float w4r[8][8], bi[8];
#pragma unroll
        for (int o = 0; o < 8; o++) {
            const float* wr = W4 + o * 8;
            float4 v0 = ld4(wr);
            float4 v1 = ld4(wr + 4);
            w4r[o][0] = v0.x; w4r[o][1] = v0.y;
            w4r[o][2] = v0.z; w4r[o][3] = v0.w;
            w4r[o][4] = v1.x; w4r[o][5] = v1.y;
            w4r[o][6] = v1.z; w4r[o][7] = v1.w;
            bi[o] = b4[o];
        }
        float sum4[8], ssq4[8];
#pragma unroll
        for (int o = 0; o < 8; o++) { sum4[o] = 0.f; ssq4[o] = 0.f; }

        uint4 v = *(const uint4*)(hbuf + h * 4096 + pbase);
#pragma unroll 1
        for (int i = h; i < NT; i += 2) {
            uint4 vn = v;
            if (i + 2 < NT)
                vn = *(const uint4*)(hbuf + (i + 2) * 4096 + pbase);
            float wf = ((diagmask >> i) & 1u) ? 1.0f : 2.0f;
            float a0 = bflo(v.x), a1 = bfhi(v.x);
            float a2 = bflo(v.y), a3 = bfhi(v.y);
            float a4 = bflo(v.z), a5 = bfhi(v.z);
            float a6 = bflo(v.w), a7 = bfhi(v.w);
            a0 = lrelu(fmaf(a0, sc3[0], sh3[0]));
            a1 = lrelu(fmaf(a1, sc3[1], sh3[1]));
            a2 = lrelu(fmaf(a2, sc3[2], sh3[2]));
            a3 = lrelu(fmaf(a3, sc3[3], sh3[3]));
            a4 = lrelu(fmaf(a4, sc3[4], sh3[4]));
            a5 = lrelu(fmaf(a5, sc3[5], sh3[5]));
            a6 = lrelu(fmaf(a6, sc3[6], sh3[6]));
            a7 = lrelu(fmaf(a7, sc3[7], sh3[7]));
            uint4 pk = make_uint4(pack2(a0, a1), pack2(a2, a3),
                                  pack2(a4, a5), pack2(a6, a7));
            *(uint4*)(hbuf + i * 4096 + pbase) = pk;   // act3 write-back
            float r[8];
            r[0] = bflo(pk.x); r[1] = bfhi(pk.x);
            r[2] = bflo(pk.y); r[3] = bfhi(pk.y);
            r[4] = bflo(pk.z); r[5] = bfhi(pk.z);
            r[6] = bflo(pk.w); r[7] = bfhi(pk.w);
            float d[8];
#pragma unroll
            for (int o = 0; o < 8; o++) d[o] = bi[o];
#pragma unroll
            for (int c = 0; c < 8; c++) {
#pragma unroll
                for (int o = 0; o < 8; o++)
                    d[o] = fmaf(r[c], w4r[o][c], d[o]);
            }
#pragma unroll
            for (int o = 0; o < 8; o++) {
                float wd = wf * d[o];
                sum4[o] += wd;
                ssq4[o] = fmaf(wd, d[o], ssq4[o]);
            }
            v = vn;
        }
#pragma unroll
        for (int off = 1; off < 64; off <<= 1) {
#pragma unroll
            for (int o = 0; o < 8; o++) {
                sum4[o] += __shfl_xor(sum4[o], off);
                ssq4[o] += __shfl_xor(ssq4[o], off);
            }
        }
        if (lane == 0) {
#pragma unroll
            for (int o = 0; o < 8; o++) {
                red[w][o]     = sum4[o];
                red[w][8 + o] = ssq4[o];
            }
        }
        __syncthreads();
        if (tid < 16) {
            float v2 = 0.f;
#pragma unroll
            for (int k = 0; k < 8; k++) v2 += red[k][tid];
            atomicAdd(stats4 + rep16 + tid, v2);
        }
    }
    gbar(flags, 4);
    if (tid < 256) sstat[tid] = aload(stats4 + tid);
    __syncthreads();

    // ---------------- phase 5: out tile + LDS-transposed mirror -----------
    {
        float w4f[8][8], b4f[8], w5r[8];
#pragma unroll
        for (int o = 0; o < 8; o++) {
            float S = 0.f, Q = 0.f;
#pragma unroll
            for (int rp = 0; rp < 16; rp++) {
                S += sstat[rp * 16 + o];
                Q += sstat[rp * 16 + 8 + o];
            }
            float mu  = S * INV_M;
            float var = fmaf(-mu, mu, Q * INV_M);
            float s   = g4[o] * rsqrtf(var + EPS);
            float shv = fmaf(-mu, s, be4[o]);
            b4f[o] = fmaf(s, b4[o], shv);
            const float* wr = W4 + o * 8;
            float4 v0 = ld4(wr);
            float4 v1 = ld4(wr + 4);
            w4f[o][0] = s * v0.x; w4f[o][1] = s * v0.y;
            w4f[o][2] = s * v0.z; w4f[o][3] = s * v0.w;
            w4f[o][4] = s * v1.x; w4f[o][5] = s * v1.y;
            w4f[o][6] = s * v1.z; w4f[o][7] = s * v1.w;
            w5r[o] = W5[o];
        }
        float b5v = b5[0];
        int half = tid >> 8;
        int lt   = tid & 255;
        int nl = lt >> 4, ml = lt & 15;
        int pbase = (lt >> 5) * 512 + (lt & 31) * 8;
        int npair = (NT + 1) >> 1;
        int buf = 0;

#pragma unroll 1
        for (int jp = 0; jp < npair; jp++) {
            int i = 2 * jp + half;
            bool act = (i < NT);
            int mt = 0, nc = 0;
            if (act) {
                int td = tdesc[i];
                mt = td >> 8; nc = td & 255;
                uint4 v = *(const uint4*)(hbuf + i * 4096 + pbase);
                float a[8];   // act3, already BN3+lrelu'd
                a[0] = bflo(v.x); a[1] = bfhi(v.x);
                a[2] = bflo(v.y); a[3] = bfhi(v.y);
                a[4] = bflo(v.z); a[5] = bfhi(v.z);
                a[6] = bflo(v.w); a[7] = bfhi(v.w);
                float accv = b5v;
#pragma unroll
                for (int o = 0; o < 8; o++) {
                    float hh = b4f[o];
#pragma unroll
                    for (int c = 0; c < 8; c++)
                        hh = fmaf(a[c], w4f[o][c], hh);
                    accv = fmaf(lrelu(hh), w5r[o], accv);
                }
                out[(size_t)(nc * 16 + nl) * NPTS + mt * 16 + ml] = accv;
                Tm[buf][half][nl * 17 + ml] = accv;
            }
            __syncthreads();
            if (act) {
                float mv = Tm[buf][half][ml * 17 + nl];
                out[(size_t)(mt * 16 + nl) * NPTS + nc * 16 + ml] = mv;
            }
            buf ^= 1;
        }
    }
}

// --------------------------------------------------------------------------
extern "C" void kernel_launch(void* const* d_in, const int* in_sizes, int n_in,
                              void* d_out, int out_size, void* d_ws,
                              size_t ws_size, hipStream_t stream) {
    const float* x   = (const float*)d_in[0];
    const float* W1  = (const float*)d_in[1];
    const float* b1  = (const float*)d_in[2];
    const float* g1  = (const float*)d_in[3];
    const float* be1 = (const float*)d_in[4];
    const float* W2  = (const float*)d_in[5];
    const float* b2  = (const float*)d_in[6];
    const float* g2  = (const float*)d_in[7];
    const float* be2 = (const float*)d_in[8];
    const float* W3  = (const float*)d_in[9];
    const float* b3  = (const float*)d_in[10];
    const float* g3  = (const float*)d_in[11];
    const float* be3 = (const float*)d_in[12];
    const float* W4  = (const float*)d_in[13];
    const float* b4  = (const float*)d_in[14];
    const float* g4  = (const float*)d_in[15];
    const float* be4 = (const float*)d_in[16];
    const float* W5  = (const float*)d_in[17];
    const float* b5  = (const float*)d_in[18];

    float* ws   = (float*)d_ws;
    float* outp = (float*)d_out;

    k_prep<<<22, 256, 0, stream>>>(ws);
    k_mega<<<NBLK, 512, 0, stream>>>(
        x, W1, b1, g1, be1, W2, b2, g2, be2, W3, b3, g3, be3,
        W4, b4, g4, be4, W5, b5, outp, ws);
}